// Round 8
// baseline (529.476 us; speedup 1.0000x reference)
//
#include <hip/hip_runtime.h>

#define NN    50000
#define EE    800000
#define EPE   850000     // EE + NN self loops
#define NPAD  50048      // multiple of 64
#define BGR   64
#define NB    196        // buckets of 256 nodes
#define CHUNK 4096       // edges per binning block
#define NBLK  208        // ceil(EPE / CHUNK)
#define BCAP  6144       // per-bucket LDS capacity in build_csr (mean 4337, 27 sigma)
#define AGCH  64         // edges per chunk in aggregate LDS (per node slot)

typedef __attribute__((ext_vector_type(8))) short bf16x8;
typedef __attribute__((ext_vector_type(4))) float f32x4;
typedef __attribute__((ext_vector_type(2))) float f32x2;
typedef __attribute__((ext_vector_type(4))) int   i32x4;

__device__ __forceinline__ float bf2f(unsigned short u) {
    return __uint_as_float(((unsigned)u) << 16);
}
__device__ __forceinline__ unsigned short f2bf(float f) {
    unsigned u = __float_as_uint(f);
    unsigned r = (u + 0x7FFFu + ((u >> 16) & 1u)) >> 16;
    return (unsigned short)r;
}
__device__ __forceinline__ float silu(float y) { return y / (1.f + __expf(-y)); }

// ---- K1: weight transpose (blk 0-3) + bucket hist (blk 4..211) --------------------
__global__ __launch_bounds__(256) void pre_kernel(const float* __restrict__ W0,
                                                  const float* __restrict__ Wg,
                                                  unsigned short* __restrict__ WT,
                                                  const int* __restrict__ eidx,
                                                  int* __restrict__ hist_blk) {
    __shared__ unsigned short tile[128][129];
    __shared__ int lh[NB];
    int b = blockIdx.x;
    if (b < 4) {
        const float* src = (b == 0) ? W0 : (Wg + (b - 1) * 16384);
        unsigned short* dst = WT + b * 16384;
        for (int i = threadIdx.x; i < 16384; i += 256) tile[i >> 7][i & 127] = f2bf(src[i]);
        __syncthreads();
        for (int i = threadIdx.x; i < 16384; i += 256) {
            int c = i >> 7, k = i & 127;
            dst[i] = tile[k][c];
        }
    } else {
        int cb = b - 4;
        for (int t = threadIdx.x; t < NB; t += 256) lh[t] = 0;
        __syncthreads();
        int base = cb * CHUNK;
#pragma unroll
        for (int j = 0; j < CHUNK / 256; ++j) {
            int i = base + j * 256 + threadIdx.x;
            if (i < EPE) {
                int d = (i < EE) ? eidx[EE + i] : (i - EE);
                atomicAdd(&lh[d >> 8], 1);
            }
        }
        __syncthreads();
        for (int t = threadIdx.x; t < NB; t += 256)
            hist_blk[cb * NB + t] = lh[t];
    }
}

// ---- K2: scan_buckets (block 0) || encoder GEMM (blocks 1..782) -------------------
__global__ __launch_bounds__(256) void scan_encoder_kernel(
    const int* __restrict__ hist_blk, int* __restrict__ blkOfs, int* __restrict__ bucketBase,
    const float* __restrict__ x, const unsigned short* __restrict__ WT,
    const float* __restrict__ b0, const float* __restrict__ g0,
    const float* __restrict__ be0, unsigned short* __restrict__ h) {
    __shared__ int tot[NB];
    __shared__ int bas[NB];
    if (blockIdx.x == 0) {
        int t = threadIdx.x;
        if (t < NB) {
            int s = 0;
            for (int k = 0; k < NBLK; ++k) s += hist_blk[k * NB + t];
            tot[t] = s;
        }
        __syncthreads();
        if (t == 0) {
            int run = 0;
            for (int b = 0; b < NB; ++b) { bas[b] = run; run += tot[b]; }
            bucketBase[NB] = EPE;
        }
        __syncthreads();
        if (t < NB) {
            int run = bas[t];
            bucketBase[t] = run;
            for (int k = 0; k < NBLK; ++k) {
                blkOfs[k * NB + t] = run;
                run += hist_blk[k * NB + t];
            }
        }
        return;
    }
    int bid = blockIdx.x - 1;
    int wave = threadIdx.x >> 6, lane = threadIdx.x & 63;
    int cl = lane & 15, q = lane >> 4;
    int row0 = bid * 64 + wave * 16;
    int rA = row0 + cl; if (rA >= NN) rA = NN - 1;
    int kq = q * 8;
    f32x4 acc[8];
#pragma unroll
    for (int t = 0; t < 8; ++t) acc[t] = (f32x4){0.f, 0.f, 0.f, 0.f};
#pragma unroll
    for (int k0 = 0; k0 < 128; k0 += 32) {
        const float* xr = x + rA * 128 + k0 + kq;
        f32x4 f0 = *(const f32x4*)(xr);
        f32x4 f1 = *(const f32x4*)(xr + 4);
        bf16x8 a;
#pragma unroll
        for (int j = 0; j < 4; ++j) {
            a[j] = (short)f2bf(f0[j]);
            a[4 + j] = (short)f2bf(f1[j]);
        }
#pragma unroll
        for (int t = 0; t < 8; ++t) {
            bf16x8 b = *(const bf16x8*)(WT + (t * 16 + cl) * 128 + k0 + kq);
            acc[t] = __builtin_amdgcn_mfma_f32_16x16x32_bf16(a, b, acc[t], 0, 0, 0);
        }
    }
    float bcol[8], gcol[8], becol[8];
#pragma unroll
    for (int t = 0; t < 8; ++t) {
        int c = t * 16 + cl;
        bcol[t] = b0[c]; gcol[t] = g0[c]; becol[t] = be0[c];
    }
#pragma unroll
    for (int r = 0; r < 4; ++r) {
        int row = row0 + q * 4 + r;
        float v[8], s = 0.f, ss = 0.f;
#pragma unroll
        for (int t = 0; t < 8; ++t) {
            v[t] = acc[t][r] + bcol[t];
            s += v[t]; ss += v[t] * v[t];
        }
#pragma unroll
        for (int m = 1; m <= 8; m <<= 1) {
            s += __shfl_xor(s, m, 64); ss += __shfl_xor(ss, m, 64);
        }
        float mu = s * (1.f / 128.f);
        float var = ss * (1.f / 128.f) - mu * mu;
        float rstd = rsqrtf(var + 1e-5f);
        if (row < NN) {
#pragma unroll
            for (int t = 0; t < 8; ++t) {
                float y = (v[t] - mu) * rstd * gcol[t] + becol[t];
                h[row * 128 + t * 16 + cl] = f2bf(silu(y));
            }
        }
    }
}

// ---- GAT GEMM body: hh8 written HEAD-INTERLEAVED: channel c -> byte (c&31)*4 + (c>>5)
__device__ __forceinline__ void gat_gemm_body(
    int bid, const unsigned short* __restrict__ h, const unsigned short* __restrict__ WT,
    const float* __restrict__ atts, const float* __restrict__ attd,
    unsigned char* __restrict__ hh8, float* __restrict__ a_s, float* __restrict__ a_d,
    float* __restrict__ es) {
    int wave = threadIdx.x >> 6, lane = threadIdx.x & 63;
    int cl = lane & 15, q = lane >> 4;
    int row0 = bid * 64 + wave * 16;
    int rA = row0 + cl; if (rA >= NN) rA = NN - 1;
    int kq = q * 8;
    f32x4 acc[8];
#pragma unroll
    for (int t = 0; t < 8; ++t) acc[t] = (f32x4){0.f, 0.f, 0.f, 0.f};
#pragma unroll
    for (int k0 = 0; k0 < 128; k0 += 32) {
        bf16x8 a = *(const bf16x8*)(h + rA * 128 + k0 + kq);
#pragma unroll
        for (int t = 0; t < 8; ++t) {
            bf16x8 b = *(const bf16x8*)(WT + (t * 16 + cl) * 128 + k0 + kq);
            acc[t] = __builtin_amdgcn_mfma_f32_16x16x32_bf16(a, b, acc[t], 0, 0, 0);
        }
    }
#pragma unroll
    for (int r = 0; r < 4; ++r) {
        int row = row0 + q * 4 + r;
        if (row < NN) {
#pragma unroll
            for (int t = 0; t < 8; ++t) {
                unsigned pk = (unsigned)__builtin_amdgcn_cvt_pk_fp8_f32(acc[t][r], acc[t][r], 0, false);
                int c = t * 16 + cl;
                hh8[row * 128 + ((c & 31) << 2) + (c >> 5)] = (unsigned char)(pk & 0xFFu);
            }
        }
    }
    float as_lo[4], as_hi[4], ad_lo[4], ad_hi[4];
#pragma unroll
    for (int hd = 0; hd < 4; ++hd) {
        as_lo[hd] = atts[hd * 32 + cl];      as_hi[hd] = atts[hd * 32 + 16 + cl];
        ad_lo[hd] = attd[hd * 32 + cl];      ad_hi[hd] = attd[hd * 32 + 16 + cl];
    }
#pragma unroll
    for (int r = 0; r < 4; ++r) {
        int row = row0 + q * 4 + r;
        float ps[4], pd[4];
#pragma unroll
        for (int hd = 0; hd < 4; ++hd) {
            float v0 = acc[2 * hd][r], v1 = acc[2 * hd + 1][r];
            ps[hd] = v0 * as_lo[hd] + v1 * as_hi[hd];
            pd[hd] = v0 * ad_lo[hd] + v1 * ad_hi[hd];
        }
#pragma unroll
        for (int m = 1; m <= 8; m <<= 1) {
#pragma unroll
            for (int hd = 0; hd < 4; ++hd) {
                ps[hd] += __shfl_xor(ps[hd], m, 64);
                pd[hd] += __shfl_xor(pd[hd], m, 64);
            }
        }
        if (row < NN && cl < 4) {
            float vs = (cl == 0) ? ps[0] : (cl == 1) ? ps[1] : (cl == 2) ? ps[2] : ps[3];
            float vd = (cl == 0) ? pd[0] : (cl == 1) ? pd[1] : (cl == 2) ? pd[2] : pd[3];
            a_s[row * 4 + cl] = vs;
            a_d[row * 4 + cl] = vd;
            float e = vs + vd;                       // self-loop logit
            es[row * 4 + cl] = (e > 0.f) ? e : 0.2f * e;
        }
    }
}

__global__ __launch_bounds__(256) void gemm_gat(
    const unsigned short* __restrict__ h, const unsigned short* __restrict__ WT,
    const float* __restrict__ atts, const float* __restrict__ attd,
    unsigned char* __restrict__ hh8, float* __restrict__ a_s, float* __restrict__ a_d,
    float* __restrict__ es) {
    gat_gemm_body(blockIdx.x, h, WT, atts, attd, hh8, a_s, a_d, es);
}

// ---- K3: bin_edges (blocks 0..207) || gemm_gat l0 (blocks 208..989) ---------------
__global__ __launch_bounds__(256) void bin_gat_kernel(
    const int* __restrict__ eidx, const int* __restrict__ blkOfs,
    unsigned* __restrict__ binned,
    const unsigned short* __restrict__ h, const unsigned short* __restrict__ WT1,
    const float* __restrict__ atts, const float* __restrict__ attd,
    unsigned char* __restrict__ hh8, float* __restrict__ a_s, float* __restrict__ a_d,
    float* __restrict__ es) {
    __shared__ unsigned staged[CHUNK];
    __shared__ int lhist[NB];
    __shared__ int lscan[NB];
    __shared__ int cnt2[NB];
    __shared__ int gofs[NB];
    if (blockIdx.x >= NBLK) {
        gat_gemm_body(blockIdx.x - NBLK, h, WT1, atts, attd, hh8, a_s, a_d, es);
        return;
    }
    int cb = blockIdx.x;
    int tid = threadIdx.x;
    for (int t = tid; t < NB; t += 256) { lhist[t] = 0; cnt2[t] = 0; }
    __syncthreads();
    int base = cb * CHUNK;
    unsigned pk[CHUNK / 256];
#pragma unroll
    for (int j = 0; j < CHUNK / 256; ++j) {
        int i = base + j * 256 + tid;
        pk[j] = 0xFFFFFFFFu;
        if (i < EPE) {
            int s, d;
            if (i < EE) { s = eidx[i]; d = eidx[EE + i]; } else { s = i - EE; d = i - EE; }
            pk[j] = ((unsigned)s << 16) | (unsigned)d;
            atomicAdd(&lhist[d >> 8], 1);
        }
    }
    __syncthreads();
    if (tid == 0) {
        int run = 0;
        for (int b = 0; b < NB; ++b) { lscan[b] = run; run += lhist[b]; }
    }
    __syncthreads();
#pragma unroll
    for (int j = 0; j < CHUNK / 256; ++j) {
        if (pk[j] != 0xFFFFFFFFu) {
            int b = (int)((pk[j] & 0xFFFFu) >> 8);
            int lp = lscan[b] + atomicAdd(&cnt2[b], 1);
            staged[lp] = pk[j];
        }
    }
    for (int t = tid; t < NB; t += 256) gofs[t] = blkOfs[cb * NB + t];
    __syncthreads();
    int nTot = lscan[NB - 1] + lhist[NB - 1];
    for (int i = tid; i < nTot; i += 256) {
        unsigned p = staged[i];
        int b = (int)((p & 0xFFFFu) >> 8);
        binned[gofs[b] + (i - lscan[b])] = p;
    }
}

// ------- per-bucket (256 nodes): counts -> offs + in-LDS sort -> contiguous csr --------
__global__ __launch_bounds__(256) void build_csr(const unsigned* __restrict__ binned,
                                                 const int* __restrict__ bucketBase,
                                                 int* __restrict__ offs,
                                                 int* __restrict__ csr) {
    __shared__ int lcsr[BCAP];
    __shared__ int lcnt[256];
    __shared__ int lcur[256];
    __shared__ int psum[256];
    int b = blockIdx.x, tid = threadIdx.x;
    int n0 = b * 256;
    int o0 = bucketBase[b];
    int nTot = bucketBase[b + 1] - o0;
    if (nTot > BCAP) nTot = BCAP;
    lcnt[tid] = 0;
    __syncthreads();
    for (int i = tid; i < nTot; i += 256)
        atomicAdd(&lcnt[binned[o0 + i] & 255u], 1);
    __syncthreads();
    int a = lcnt[tid];
    psum[tid] = a;
    __syncthreads();
    for (int d = 1; d < 256; d <<= 1) {
        int v = (tid >= d) ? psum[tid - d] : 0;
        __syncthreads(); psum[tid] += v; __syncthreads();
    }
    int excl = psum[tid] - a;
    lcur[tid] = excl;
    int node = n0 + tid;
    if (node < NN) offs[node] = o0 + excl;
    if (b == 0 && tid == 0) offs[NN] = EPE;
    __syncthreads();
    for (int i = tid; i < nTot; i += 256) {
        unsigned p = binned[o0 + i];
        int pos = atomicAdd(&lcur[p & 255u], 1);
        if (pos < BCAP) lcsr[pos] = (int)(p >> 16);
    }
    __syncthreads();
    for (int i = tid; i < nTot; i += 256)
        csr[o0 + i] = lcsr[i];
}

// ---- aggregation (round-1 structure, serial phase deepened to 8 gathers in flight).
// 2 nodes/wave (8/block). Weight phase: 32-lane half computes (s, w4) per edge -> LDS.
// Serial phase: half walks its node's edges; per 8 edges: 2 ds_read_b128 (s8), then
//   8 independent u32 gathers issued together (head-interleaved hh8), then per-edge
//   w read + FMA. Epilogue loads in epilogue only (round-5 spill lesson).
__global__ __launch_bounds__(256) void gat_aggregate(
    const int* __restrict__ offs, const int* __restrict__ csr,
    const float* __restrict__ a_s, const float* __restrict__ a_d,
    const float* __restrict__ es, const unsigned char* __restrict__ hh8,
    unsigned short* __restrict__ h,
    const float* __restrict__ bg, const float* __restrict__ gg,
    const float* __restrict__ bgg) {
    __shared__ int   lss[8][AGCH];
    __shared__ f32x4 lww[8][AGCH];
    int wv = threadIdx.x >> 6;
    int lane = threadIdx.x & 63;
    int half = lane >> 5;
    int l32 = lane & 31;
    int ns = wv * 2 + half;
    int node = blockIdx.x * 8 + ns;     // NN % 8 == 0
    int e0 = offs[node], e1 = offs[node + 1];
    f32x4 ad4 = *(const f32x4*)(a_d + node * 4);
    f32x4 e4  = *(const f32x4*)(es  + node * 4);
    f32x4 dacc = (f32x4){0.f, 0.f, 0.f, 0.f};
    f32x4 xacc = (f32x4){0.f, 0.f, 0.f, 0.f};
    const unsigned char* hp = hh8 + l32 * 4;
    for (int base = e0; base < e1; base += AGCH) {
        int cend = min(e1, base + AGCH);
        int n = cend - base;
        // weight phase: each lane of the half computes all 4 head weights of its edges
        for (int e = base + l32; e < cend; e += 32) {
            int s = csr[e];
            f32x4 as = *(const f32x4*)(a_s + s * 4);
            f32x4 w;
#pragma unroll
            for (int k = 0; k < 4; ++k) {
                float qq = as[k] + ad4[k];
                qq = (qq > 0.f) ? qq : 0.2f * qq;
                w[k] = __expf(qq - e4[k]);
                dacc[k] += w[k];
            }
            lss[ns][e - base] = s;
            lww[ns][e - base] = w;
        }
        asm volatile("s_waitcnt lgkmcnt(0)" ::: "memory");
        // serial accumulate: all 32 lanes walk all edges; 8 gathers in flight per group
        int j = 0;
        for (; j + 8 <= n; j += 8) {
            i32x4 sa = *(const i32x4*)(&lss[ns][j]);
            i32x4 sb = *(const i32x4*)(&lss[ns][j + 4]);
            unsigned v0 = *(const unsigned*)(hp + ((long)sa[0] << 7));
            unsigned v1 = *(const unsigned*)(hp + ((long)sa[1] << 7));
            unsigned v2 = *(const unsigned*)(hp + ((long)sa[2] << 7));
            unsigned v3 = *(const unsigned*)(hp + ((long)sa[3] << 7));
            unsigned v4 = *(const unsigned*)(hp + ((long)sb[0] << 7));
            unsigned v5 = *(const unsigned*)(hp + ((long)sb[1] << 7));
            unsigned v6 = *(const unsigned*)(hp + ((long)sb[2] << 7));
            unsigned v7 = *(const unsigned*)(hp + ((long)sb[3] << 7));
#define AG_EDGE(vv, idx)                                                            \
            {                                                                       \
                f32x4 w = lww[ns][j + (idx)];                                       \
                f32x2 lo = __builtin_amdgcn_cvt_pk_f32_fp8((vv), false);            \
                f32x2 hi = __builtin_amdgcn_cvt_pk_f32_fp8((vv), true);             \
                xacc[0] += w[0] * lo[0]; xacc[1] += w[1] * lo[1];                   \
                xacc[2] += w[2] * hi[0]; xacc[3] += w[3] * hi[1];                   \
            }
            AG_EDGE(v0, 0) AG_EDGE(v1, 1) AG_EDGE(v2, 2) AG_EDGE(v3, 3)
            AG_EDGE(v4, 4) AG_EDGE(v5, 5) AG_EDGE(v6, 6) AG_EDGE(v7, 7)
        }
        for (; j + 4 <= n; j += 4) {
            i32x4 sa = *(const i32x4*)(&lss[ns][j]);
            unsigned v0 = *(const unsigned*)(hp + ((long)sa[0] << 7));
            unsigned v1 = *(const unsigned*)(hp + ((long)sa[1] << 7));
            unsigned v2 = *(const unsigned*)(hp + ((long)sa[2] << 7));
            unsigned v3 = *(const unsigned*)(hp + ((long)sa[3] << 7));
            AG_EDGE(v0, 0) AG_EDGE(v1, 1) AG_EDGE(v2, 2) AG_EDGE(v3, 3)
        }
        for (; j < n; ++j) {
            int s0 = lss[ns][j];
            unsigned v0 = *(const unsigned*)(hp + ((long)s0 << 7));
            AG_EDGE(v0, 0)
        }
#undef AG_EDGE
        if (cend < e1)
            asm volatile("s_waitcnt lgkmcnt(0)" ::: "memory");
    }
    // per-head denominators: reduce within the 32-lane half
#pragma unroll
    for (int m = 1; m <= 16; m <<= 1) {
#pragma unroll
        for (int k = 0; k < 4; ++k) dacc[k] += __shfl_xor(dacc[k], m, 64);
    }
    float o[4], s = 0.f, ss = 0.f;
#pragma unroll
    for (int k = 0; k < 4; ++k) {
        int c = (k << 5) + l32;
        o[k] = xacc[k] / dacc[k] + bg[c];
        s += o[k]; ss += o[k] * o[k];
    }
#pragma unroll
    for (int m = 1; m <= 16; m <<= 1) {   // reduce within the 32-lane half
        s += __shfl_xor(s, m, 64); ss += __shfl_xor(ss, m, 64);
    }
    float mu = s * (1.f / 128.f);
    float var = ss * (1.f / 128.f) - mu * mu;
    float rstd = rsqrtf(var + 1e-5f);
#pragma unroll
    for (int k = 0; k < 4; ++k) {
        int c = (k << 5) + l32;
        float y = (o[k] - mu) * rstd * gg[c] + bgg[c];
        float r = silu(y) + bf2f(h[node * 128 + c]);
        h[node * 128 + c] = f2bf(r);
    }
}

// ---- head (pool fused): per graph g, sum own rows of h (batch sorted), then
// silu(LN(mean @ Wp + bp)) -> f32 out ------------------------------------------------
__global__ void final_kernel(const unsigned short* __restrict__ h, const int* __restrict__ batch,
                             const float* __restrict__ Wp, const float* __restrict__ bp,
                             const float* __restrict__ gp, const float* __restrict__ bep,
                             float* __restrict__ out) {
    __shared__ float p[128];
    __shared__ float red[128];
    __shared__ int bounds[2];
    int g = blockIdx.x, c = threadIdx.x;
    if (c == 0) {
        int lo = 0, hi = NN;
        while (lo < hi) { int m = (lo + hi) >> 1; if (batch[m] < g) lo = m + 1; else hi = m; }
        bounds[0] = lo;
        int lo2 = lo, hi2 = NN;
        while (lo2 < hi2) { int m = (lo2 + hi2) >> 1; if (batch[m] < g + 1) lo2 = m + 1; else hi2 = m; }
        bounds[1] = lo2;
    }
    __syncthreads();
    int lo = bounds[0], hi = bounds[1];
    float acc0 = 0.f;
    for (int r = lo; r < hi; ++r)
        acc0 += bf2f(h[r * 128 + c]);
    float cnt = (float)(hi - lo); if (cnt < 1.f) cnt = 1.f;
    p[c] = acc0 / cnt;
    __syncthreads();
    float acc = bp[c];
    for (int k = 0; k < 128; ++k) acc += p[k] * Wp[k * 128 + c];
    red[c] = acc;
    __syncthreads();
    if (c < 64) {
        float s = red[c] + red[c + 64];
#pragma unroll
        for (int m = 1; m <= 32; m <<= 1) s += __shfl_xor(s, m, 64);
        if (c == 0) red[0] = s;
    }
    __syncthreads();
    float mu = red[0] * (1.f / 128.f);
    __syncthreads();
    float dv = acc - mu;
    red[c] = dv * dv;
    __syncthreads();
    if (c < 64) {
        float s = red[c] + red[c + 64];
#pragma unroll
        for (int m = 1; m <= 32; m <<= 1) s += __shfl_xor(s, m, 64);
        if (c == 0) red[0] = s;
    }
    __syncthreads();
    float var = red[0] * (1.f / 128.f);
    float rstd = rsqrtf(var + 1e-5f);
    float y = dv * rstd * gp[c] + bep[c];
    out[g * 128 + c] = silu(y);
}

extern "C" void kernel_launch(void* const* d_in, const int* in_sizes, int n_in,
                              void* d_out, int out_size, void* d_ws, size_t ws_size,
                              hipStream_t stream) {
    const float* x    = (const float*)d_in[0];
    const int*   eidx = (const int*)d_in[1];
    const int*   batch= (const int*)d_in[2];
    const float* W0   = (const float*)d_in[3];
    const float* b0   = (const float*)d_in[4];
    const float* g0   = (const float*)d_in[5];
    const float* be0  = (const float*)d_in[6];
    const float* Wg   = (const float*)d_in[7];
    const float* atts = (const float*)d_in[8];
    const float* attd = (const float*)d_in[9];
    const float* bg   = (const float*)d_in[10];
    const float* gg   = (const float*)d_in[11];
    const float* bgg  = (const float*)d_in[12];
    const float* Wp   = (const float*)d_in[13];
    const float* bp   = (const float*)d_in[14];
    const float* gp   = (const float*)d_in[15];
    const float* bep  = (const float*)d_in[16];

    char* ws = (char*)d_ws;
    size_t off = 0;
    auto alloc = [&](size_t bytes) {
        void* p = ws + off;
        off = (off + bytes + 255) & ~(size_t)255;
        return p;
    };
    unsigned short* h        = (unsigned short*)alloc((size_t)NPAD * 128 * 2);
    unsigned char*  hh8      = (unsigned char*)alloc((size_t)NN * 128);
    float*          a_s      = (float*)alloc((size_t)NN * 4 * 4);
    float*          a_d      = (float*)alloc((size_t)NN * 4 * 4);
    float*          es       = (float*)alloc((size_t)NN * 4 * 4);
    int*            offs     = (int*)alloc((size_t)(NN + 1) * 4);
    int*            csr      = (int*)alloc((size_t)EPE * 4);
    unsigned*       binned   = (unsigned*)alloc((size_t)EPE * 4);
    int*            hist_blk = (int*)alloc((size_t)NBLK * NB * 4);
    int*            blkOfs   = (int*)alloc((size_t)NBLK * NB * 4);
    int*            bktBase  = (int*)alloc((size_t)(NB + 1) * 4);
    unsigned short* WT       = (unsigned short*)alloc(4 * 16384 * 2);

    // K1: transpose + per-chunk hist (all independent)
    pre_kernel<<<4 + NBLK, 256, 0, stream>>>(W0, Wg, WT, eidx, hist_blk);
    // K2: bucket scan (1 block) hidden under encoder GEMM
    scan_encoder_kernel<<<1 + NPAD / 64, 256, 0, stream>>>(hist_blk, blkOfs, bktBase,
                                                           x, WT, b0, g0, be0, h);
    // K3: edge binning hidden under GAT GEMM layer 0
    bin_gat_kernel<<<NBLK + NPAD / 64, 256, 0, stream>>>(eidx, blkOfs, binned,
                                                         h, WT + 16384, atts, attd,
                                                         hh8, a_s, a_d, es);
    build_csr<<<NB, 256, 0, stream>>>(binned, bktBase, offs, csr);

    gat_aggregate<<<NN / 8, 256, 0, stream>>>(offs, csr, a_s, a_d, es, hh8, h,
                                              bg, gg, bgg);
    for (int l = 1; l < 3; ++l) {
        gemm_gat<<<NPAD / 64, 256, 0, stream>>>(h, WT + (l + 1) * 16384,
                                                atts + l * 128, attd + l * 128,
                                                hh8, a_s, a_d, es);
        gat_aggregate<<<NN / 8, 256, 0, stream>>>(offs, csr, a_s, a_d, es, hh8, h,
                                                  bg + l * 128, gg + l * 128,
                                                  bgg + l * 128);
    }
    final_kernel<<<BGR, 128, 0, stream>>>(h, batch, Wp, bp, gp, bep, (float*)d_out);
}

// Round 9
// 340.362 us; speedup vs baseline: 1.5556x; 1.5556x over previous
//
#include <hip/hip_runtime.h>

#define NN    50000
#define EE    800000
#define EPE   850000     // EE + NN self loops
#define NPAD  50048      // multiple of 64
#define BGR   64
#define NB    196        // buckets of 256 nodes
#define CHUNK 4096       // edges per binning block
#define NBLK  208        // ceil(EPE / CHUNK)
#define BCAP  6144       // per-bucket LDS capacity in build_csr (mean 4337, 27 sigma)
#define AGCH  64         // edges per chunk in aggregate LDS (per node slot)

typedef __attribute__((ext_vector_type(8))) short bf16x8;
typedef __attribute__((ext_vector_type(4))) float f32x4;
typedef __attribute__((ext_vector_type(2))) float f32x2;
typedef __attribute__((ext_vector_type(4))) int   i32x4;

__device__ __forceinline__ float bf2f(unsigned short u) {
    return __uint_as_float(((unsigned)u) << 16);
}
__device__ __forceinline__ unsigned short f2bf(float f) {
    unsigned u = __float_as_uint(f);
    unsigned r = (u + 0x7FFFu + ((u >> 16) & 1u)) >> 16;
    return (unsigned short)r;
}
__device__ __forceinline__ float silu(float y) { return y / (1.f + __expf(-y)); }

// ---- K1: weight transpose (blk 0-3) + pooled zero (blk 4-35) + bucket hist (blk 36..243)
__global__ __launch_bounds__(256) void pre_kernel(const float* __restrict__ W0,
                                                  const float* __restrict__ Wg,
                                                  unsigned short* __restrict__ WT,
                                                  float* __restrict__ pooled,
                                                  const int* __restrict__ eidx,
                                                  int* __restrict__ hist_blk) {
    __shared__ unsigned short tile[128][129];
    __shared__ int lh[NB];
    int b = blockIdx.x;
    if (b < 4) {
        const float* src = (b == 0) ? W0 : (Wg + (b - 1) * 16384);
        unsigned short* dst = WT + b * 16384;
        for (int i = threadIdx.x; i < 16384; i += 256) tile[i >> 7][i & 127] = f2bf(src[i]);
        __syncthreads();
        for (int i = threadIdx.x; i < 16384; i += 256) {
            int c = i >> 7, k = i & 127;
            dst[i] = tile[k][c];
        }
    } else if (b < 36) {
        int j = (b - 4) * 256 + threadIdx.x;
        pooled[j] = 0.f;   // 32*256 == BGR*128 exactly
    } else {
        int cb = b - 36;
        for (int t = threadIdx.x; t < NB; t += 256) lh[t] = 0;
        __syncthreads();
        int base = cb * CHUNK;
#pragma unroll
        for (int j = 0; j < CHUNK / 256; ++j) {
            int i = base + j * 256 + threadIdx.x;
            if (i < EPE) {
                int d = (i < EE) ? eidx[EE + i] : (i - EE);
                atomicAdd(&lh[d >> 8], 1);
            }
        }
        __syncthreads();
        for (int t = threadIdx.x; t < NB; t += 256)
            hist_blk[cb * NB + t] = lh[t];
    }
}

// ---- K2: scan_buckets (block 0) || encoder GEMM (blocks 1..782) -------------------
__global__ __launch_bounds__(256) void scan_encoder_kernel(
    const int* __restrict__ hist_blk, int* __restrict__ blkOfs, int* __restrict__ bucketBase,
    const float* __restrict__ x, const unsigned short* __restrict__ WT,
    const float* __restrict__ b0, const float* __restrict__ g0,
    const float* __restrict__ be0, unsigned short* __restrict__ h) {
    __shared__ int tot[NB];
    __shared__ int bas[NB];
    if (blockIdx.x == 0) {
        int t = threadIdx.x;
        if (t < NB) {
            int s = 0;
            for (int k = 0; k < NBLK; ++k) s += hist_blk[k * NB + t];
            tot[t] = s;
        }
        __syncthreads();
        if (t == 0) {
            int run = 0;
            for (int b = 0; b < NB; ++b) { bas[b] = run; run += tot[b]; }
            bucketBase[NB] = EPE;
        }
        __syncthreads();
        if (t < NB) {
            int run = bas[t];
            bucketBase[t] = run;
            for (int k = 0; k < NBLK; ++k) {
                blkOfs[k * NB + t] = run;
                run += hist_blk[k * NB + t];
            }
        }
        return;
    }
    int bid = blockIdx.x - 1;
    int wave = threadIdx.x >> 6, lane = threadIdx.x & 63;
    int cl = lane & 15, q = lane >> 4;
    int row0 = bid * 64 + wave * 16;
    int rA = row0 + cl; if (rA >= NN) rA = NN - 1;
    int kq = q * 8;
    f32x4 acc[8];
#pragma unroll
    for (int t = 0; t < 8; ++t) acc[t] = (f32x4){0.f, 0.f, 0.f, 0.f};
#pragma unroll
    for (int k0 = 0; k0 < 128; k0 += 32) {
        const float* xr = x + rA * 128 + k0 + kq;
        f32x4 f0 = *(const f32x4*)(xr);
        f32x4 f1 = *(const f32x4*)(xr + 4);
        bf16x8 a;
#pragma unroll
        for (int j = 0; j < 4; ++j) {
            a[j] = (short)f2bf(f0[j]);
            a[4 + j] = (short)f2bf(f1[j]);
        }
#pragma unroll
        for (int t = 0; t < 8; ++t) {
            bf16x8 b = *(const bf16x8*)(WT + (t * 16 + cl) * 128 + k0 + kq);
            acc[t] = __builtin_amdgcn_mfma_f32_16x16x32_bf16(a, b, acc[t], 0, 0, 0);
        }
    }
    float bcol[8], gcol[8], becol[8];
#pragma unroll
    for (int t = 0; t < 8; ++t) {
        int c = t * 16 + cl;
        bcol[t] = b0[c]; gcol[t] = g0[c]; becol[t] = be0[c];
    }
#pragma unroll
    for (int r = 0; r < 4; ++r) {
        int row = row0 + q * 4 + r;
        float v[8], s = 0.f, ss = 0.f;
#pragma unroll
        for (int t = 0; t < 8; ++t) {
            v[t] = acc[t][r] + bcol[t];
            s += v[t]; ss += v[t] * v[t];
        }
#pragma unroll
        for (int m = 1; m <= 8; m <<= 1) {
            s += __shfl_xor(s, m, 64); ss += __shfl_xor(ss, m, 64);
        }
        float mu = s * (1.f / 128.f);
        float var = ss * (1.f / 128.f) - mu * mu;
        float rstd = rsqrtf(var + 1e-5f);
        if (row < NN) {
#pragma unroll
            for (int t = 0; t < 8; ++t) {
                float y = (v[t] - mu) * rstd * gcol[t] + becol[t];
                h[row * 128 + t * 16 + cl] = f2bf(silu(y));
            }
        }
    }
}

// ---- GAT GEMM body: hh8 written HEAD-INTERLEAVED: channel c -> byte (c&31)*4 + (c>>5)
__device__ __forceinline__ void gat_gemm_body(
    int bid, const unsigned short* __restrict__ h, const unsigned short* __restrict__ WT,
    const float* __restrict__ atts, const float* __restrict__ attd,
    unsigned char* __restrict__ hh8, float* __restrict__ a_s, float* __restrict__ a_d,
    float* __restrict__ es) {
    int wave = threadIdx.x >> 6, lane = threadIdx.x & 63;
    int cl = lane & 15, q = lane >> 4;
    int row0 = bid * 64 + wave * 16;
    int rA = row0 + cl; if (rA >= NN) rA = NN - 1;
    int kq = q * 8;
    f32x4 acc[8];
#pragma unroll
    for (int t = 0; t < 8; ++t) acc[t] = (f32x4){0.f, 0.f, 0.f, 0.f};
#pragma unroll
    for (int k0 = 0; k0 < 128; k0 += 32) {
        bf16x8 a = *(const bf16x8*)(h + rA * 128 + k0 + kq);
#pragma unroll
        for (int t = 0; t < 8; ++t) {
            bf16x8 b = *(const bf16x8*)(WT + (t * 16 + cl) * 128 + k0 + kq);
            acc[t] = __builtin_amdgcn_mfma_f32_16x16x32_bf16(a, b, acc[t], 0, 0, 0);
        }
    }
#pragma unroll
    for (int r = 0; r < 4; ++r) {
        int row = row0 + q * 4 + r;
        if (row < NN) {
#pragma unroll
            for (int t = 0; t < 8; ++t) {
                unsigned pk = (unsigned)__builtin_amdgcn_cvt_pk_fp8_f32(acc[t][r], acc[t][r], 0, false);
                int c = t * 16 + cl;
                hh8[row * 128 + ((c & 31) << 2) + (c >> 5)] = (unsigned char)(pk & 0xFFu);
            }
        }
    }
    float as_lo[4], as_hi[4], ad_lo[4], ad_hi[4];
#pragma unroll
    for (int hd = 0; hd < 4; ++hd) {
        as_lo[hd] = atts[hd * 32 + cl];      as_hi[hd] = atts[hd * 32 + 16 + cl];
        ad_lo[hd] = attd[hd * 32 + cl];      ad_hi[hd] = attd[hd * 32 + 16 + cl];
    }
#pragma unroll
    for (int r = 0; r < 4; ++r) {
        int row = row0 + q * 4 + r;
        float ps[4], pd[4];
#pragma unroll
        for (int hd = 0; hd < 4; ++hd) {
            float v0 = acc[2 * hd][r], v1 = acc[2 * hd + 1][r];
            ps[hd] = v0 * as_lo[hd] + v1 * as_hi[hd];
            pd[hd] = v0 * ad_lo[hd] + v1 * ad_hi[hd];
        }
#pragma unroll
        for (int m = 1; m <= 8; m <<= 1) {
#pragma unroll
            for (int hd = 0; hd < 4; ++hd) {
                ps[hd] += __shfl_xor(ps[hd], m, 64);
                pd[hd] += __shfl_xor(pd[hd], m, 64);
            }
        }
        if (row < NN && cl < 4) {
            float vs = (cl == 0) ? ps[0] : (cl == 1) ? ps[1] : (cl == 2) ? ps[2] : ps[3];
            float vd = (cl == 0) ? pd[0] : (cl == 1) ? pd[1] : (cl == 2) ? pd[2] : pd[3];
            a_s[row * 4 + cl] = vs;
            a_d[row * 4 + cl] = vd;
            float e = vs + vd;                       // self-loop logit
            es[row * 4 + cl] = (e > 0.f) ? e : 0.2f * e;
        }
    }
}

__global__ __launch_bounds__(256) void gemm_gat(
    const unsigned short* __restrict__ h, const unsigned short* __restrict__ WT,
    const float* __restrict__ atts, const float* __restrict__ attd,
    unsigned char* __restrict__ hh8, float* __restrict__ a_s, float* __restrict__ a_d,
    float* __restrict__ es) {
    gat_gemm_body(blockIdx.x, h, WT, atts, attd, hh8, a_s, a_d, es);
}

// ---- K3: bin_edges (blocks 0..207) || gemm_gat l0 (blocks 208..989) ---------------
__global__ __launch_bounds__(256) void bin_gat_kernel(
    const int* __restrict__ eidx, const int* __restrict__ blkOfs,
    unsigned* __restrict__ binned,
    const unsigned short* __restrict__ h, const unsigned short* __restrict__ WT1,
    const float* __restrict__ atts, const float* __restrict__ attd,
    unsigned char* __restrict__ hh8, float* __restrict__ a_s, float* __restrict__ a_d,
    float* __restrict__ es) {
    __shared__ unsigned staged[CHUNK];
    __shared__ int lhist[NB];
    __shared__ int lscan[NB];
    __shared__ int cnt2[NB];
    __shared__ int gofs[NB];
    if (blockIdx.x >= NBLK) {
        gat_gemm_body(blockIdx.x - NBLK, h, WT1, atts, attd, hh8, a_s, a_d, es);
        return;
    }
    int cb = blockIdx.x;
    int tid = threadIdx.x;
    for (int t = tid; t < NB; t += 256) { lhist[t] = 0; cnt2[t] = 0; }
    __syncthreads();
    int base = cb * CHUNK;
    unsigned pk[CHUNK / 256];
#pragma unroll
    for (int j = 0; j < CHUNK / 256; ++j) {
        int i = base + j * 256 + tid;
        pk[j] = 0xFFFFFFFFu;
        if (i < EPE) {
            int s, d;
            if (i < EE) { s = eidx[i]; d = eidx[EE + i]; } else { s = i - EE; d = i - EE; }
            pk[j] = ((unsigned)s << 16) | (unsigned)d;
            atomicAdd(&lhist[d >> 8], 1);
        }
    }
    __syncthreads();
    if (tid == 0) {
        int run = 0;
        for (int b = 0; b < NB; ++b) { lscan[b] = run; run += lhist[b]; }
    }
    __syncthreads();
#pragma unroll
    for (int j = 0; j < CHUNK / 256; ++j) {
        if (pk[j] != 0xFFFFFFFFu) {
            int b = (int)((pk[j] & 0xFFFFu) >> 8);
            int lp = lscan[b] + atomicAdd(&cnt2[b], 1);
            staged[lp] = pk[j];
        }
    }
    for (int t = tid; t < NB; t += 256) gofs[t] = blkOfs[cb * NB + t];
    __syncthreads();
    int nTot = lscan[NB - 1] + lhist[NB - 1];
    for (int i = tid; i < nTot; i += 256) {
        unsigned p = staged[i];
        int b = (int)((p & 0xFFFFu) >> 8);
        binned[gofs[b] + (i - lscan[b])] = p;
    }
}

// ------- per-bucket (256 nodes): counts -> offs + in-LDS sort -> contiguous csr --------
__global__ __launch_bounds__(256) void build_csr(const unsigned* __restrict__ binned,
                                                 const int* __restrict__ bucketBase,
                                                 int* __restrict__ offs,
                                                 int* __restrict__ csr) {
    __shared__ int lcsr[BCAP];
    __shared__ int lcnt[256];
    __shared__ int lcur[256];
    __shared__ int psum[256];
    int b = blockIdx.x, tid = threadIdx.x;
    int n0 = b * 256;
    int o0 = bucketBase[b];
    int nTot = bucketBase[b + 1] - o0;
    if (nTot > BCAP) nTot = BCAP;
    lcnt[tid] = 0;
    __syncthreads();
    for (int i = tid; i < nTot; i += 256)
        atomicAdd(&lcnt[binned[o0 + i] & 255u], 1);
    __syncthreads();
    int a = lcnt[tid];
    psum[tid] = a;
    __syncthreads();
    for (int d = 1; d < 256; d <<= 1) {
        int v = (tid >= d) ? psum[tid - d] : 0;
        __syncthreads(); psum[tid] += v; __syncthreads();
    }
    int excl = psum[tid] - a;
    lcur[tid] = excl;
    int node = n0 + tid;
    if (node < NN) offs[node] = o0 + excl;
    if (b == 0 && tid == 0) offs[NN] = EPE;
    __syncthreads();
    for (int i = tid; i < nTot; i += 256) {
        unsigned p = binned[o0 + i];
        int pos = atomicAdd(&lcur[p & 255u], 1);
        if (pos < BCAP) lcsr[pos] = (int)(p >> 16);
    }
    __syncthreads();
    for (int i = tid; i < nTot; i += 256)
        csr[o0 + i] = lcsr[i];
}

// ---- aggregation (round-1 structure, 8 gathers in flight per group).
// 2 nodes/wave (8/block). Weight phase: 32-lane half computes (s, w4) per edge -> LDS.
// Serial phase: half walks its node's edges; per 8 edges: 2 ds_read_b128 (s8), then
//   8 independent u32 gathers (head-interleaved hh8), then per-edge w read + FMA.
// Epilogue loads in epilogue only (round-5 spill lesson). Pool NOT fused (round-6
// atomic-contention lesson; round-8 final-fusion occupancy lesson).
__global__ __launch_bounds__(256) void gat_aggregate(
    const int* __restrict__ offs, const int* __restrict__ csr,
    const float* __restrict__ a_s, const float* __restrict__ a_d,
    const float* __restrict__ es, const unsigned char* __restrict__ hh8,
    unsigned short* __restrict__ h,
    const float* __restrict__ bg, const float* __restrict__ gg,
    const float* __restrict__ bgg) {
    __shared__ int   lss[8][AGCH];
    __shared__ f32x4 lww[8][AGCH];
    int wv = threadIdx.x >> 6;
    int lane = threadIdx.x & 63;
    int half = lane >> 5;
    int l32 = lane & 31;
    int ns = wv * 2 + half;
    int node = blockIdx.x * 8 + ns;     // NN % 8 == 0
    int e0 = offs[node], e1 = offs[node + 1];
    f32x4 ad4 = *(const f32x4*)(a_d + node * 4);
    f32x4 e4  = *(const f32x4*)(es  + node * 4);
    f32x4 dacc = (f32x4){0.f, 0.f, 0.f, 0.f};
    f32x4 xacc = (f32x4){0.f, 0.f, 0.f, 0.f};
    const unsigned char* hp = hh8 + l32 * 4;
    for (int base = e0; base < e1; base += AGCH) {
        int cend = min(e1, base + AGCH);
        int n = cend - base;
        // weight phase: each lane of the half computes all 4 head weights of its edges
        for (int e = base + l32; e < cend; e += 32) {
            int s = csr[e];
            f32x4 as = *(const f32x4*)(a_s + s * 4);
            f32x4 w;
#pragma unroll
            for (int k = 0; k < 4; ++k) {
                float qq = as[k] + ad4[k];
                qq = (qq > 0.f) ? qq : 0.2f * qq;
                w[k] = __expf(qq - e4[k]);
                dacc[k] += w[k];
            }
            lss[ns][e - base] = s;
            lww[ns][e - base] = w;
        }
        asm volatile("s_waitcnt lgkmcnt(0)" ::: "memory");
        // serial accumulate: all 32 lanes walk all edges; 8 gathers in flight per group
        int j = 0;
        for (; j + 8 <= n; j += 8) {
            i32x4 sa = *(const i32x4*)(&lss[ns][j]);
            i32x4 sb = *(const i32x4*)(&lss[ns][j + 4]);
            unsigned v0 = *(const unsigned*)(hp + ((long)sa[0] << 7));
            unsigned v1 = *(const unsigned*)(hp + ((long)sa[1] << 7));
            unsigned v2 = *(const unsigned*)(hp + ((long)sa[2] << 7));
            unsigned v3 = *(const unsigned*)(hp + ((long)sa[3] << 7));
            unsigned v4 = *(const unsigned*)(hp + ((long)sb[0] << 7));
            unsigned v5 = *(const unsigned*)(hp + ((long)sb[1] << 7));
            unsigned v6 = *(const unsigned*)(hp + ((long)sb[2] << 7));
            unsigned v7 = *(const unsigned*)(hp + ((long)sb[3] << 7));
#define AG_EDGE(vv, idx)                                                            \
            {                                                                       \
                f32x4 w = lww[ns][j + (idx)];                                       \
                f32x2 lo = __builtin_amdgcn_cvt_pk_f32_fp8((vv), false);            \
                f32x2 hi = __builtin_amdgcn_cvt_pk_f32_fp8((vv), true);             \
                xacc[0] += w[0] * lo[0]; xacc[1] += w[1] * lo[1];                   \
                xacc[2] += w[2] * hi[0]; xacc[3] += w[3] * hi[1];                   \
            }
            AG_EDGE(v0, 0) AG_EDGE(v1, 1) AG_EDGE(v2, 2) AG_EDGE(v3, 3)
            AG_EDGE(v4, 4) AG_EDGE(v5, 5) AG_EDGE(v6, 6) AG_EDGE(v7, 7)
        }
        for (; j + 4 <= n; j += 4) {
            i32x4 sa = *(const i32x4*)(&lss[ns][j]);
            unsigned v0 = *(const unsigned*)(hp + ((long)sa[0] << 7));
            unsigned v1 = *(const unsigned*)(hp + ((long)sa[1] << 7));
            unsigned v2 = *(const unsigned*)(hp + ((long)sa[2] << 7));
            unsigned v3 = *(const unsigned*)(hp + ((long)sa[3] << 7));
            AG_EDGE(v0, 0) AG_EDGE(v1, 1) AG_EDGE(v2, 2) AG_EDGE(v3, 3)
        }
        for (; j < n; ++j) {
            int s0 = lss[ns][j];
            unsigned v0 = *(const unsigned*)(hp + ((long)s0 << 7));
            AG_EDGE(v0, 0)
        }
#undef AG_EDGE
        if (cend < e1)
            asm volatile("s_waitcnt lgkmcnt(0)" ::: "memory");
    }
    // per-head denominators: reduce within the 32-lane half
#pragma unroll
    for (int m = 1; m <= 16; m <<= 1) {
#pragma unroll
        for (int k = 0; k < 4; ++k) dacc[k] += __shfl_xor(dacc[k], m, 64);
    }
    float o[4], s = 0.f, ss = 0.f;
#pragma unroll
    for (int k = 0; k < 4; ++k) {
        int c = (k << 5) + l32;
        o[k] = xacc[k] / dacc[k] + bg[c];
        s += o[k]; ss += o[k] * o[k];
    }
#pragma unroll
    for (int m = 1; m <= 16; m <<= 1) {   // reduce within the 32-lane half
        s += __shfl_xor(s, m, 64); ss += __shfl_xor(ss, m, 64);
    }
    float mu = s * (1.f / 128.f);
    float var = ss * (1.f / 128.f) - mu * mu;
    float rstd = rsqrtf(var + 1e-5f);
#pragma unroll
    for (int k = 0; k < 4; ++k) {
        int c = (k << 5) + l32;
        float y = (o[k] - mu) * rstd * gg[c] + bgg[c];
        float r = silu(y) + bf2f(h[node * 128 + c]);
        h[node * 128 + c] = f2bf(r);
    }
}

// ---- mean pool per graph (batch sorted -> run reduction, ~2 atomics per block/col) ----
__global__ void pool_kernel(const unsigned short* __restrict__ h, const int* __restrict__ batch,
                            float* __restrict__ pooled) {
    int c = threadIdx.x;
    int r0 = blockIdx.x * 64;
    int rend = r0 + 64; if (rend > NN) rend = NN;
    int cur = batch[r0];
    float acc = 0.f;
    for (int r = r0; r < rend; ++r) {
        int b = batch[r];
        float v = bf2f(h[r * 128 + c]);
        if (b != cur) {
            atomicAdd(&pooled[cur * 128 + c], acc);
            acc = 0.f; cur = b;
        }
        acc += v;
    }
    atomicAdd(&pooled[cur * 128 + c], acc);
}

// ---------------- head: silu(LN(pooled/cnt @ Wp + bp)) -> f32 out ----------------
__global__ void final_kernel(const float* __restrict__ pooled, const int* __restrict__ batch,
                             const float* __restrict__ Wp, const float* __restrict__ bp,
                             const float* __restrict__ gp, const float* __restrict__ bep,
                             float* __restrict__ out) {
    __shared__ float p[128];
    __shared__ float red[128];
    __shared__ int bounds[2];
    int g = blockIdx.x, c = threadIdx.x;
    if (c == 0) {
        int lo = 0, hi = NN;
        while (lo < hi) { int m = (lo + hi) >> 1; if (batch[m] < g) lo = m + 1; else hi = m; }
        bounds[0] = lo;
        int lo2 = lo, hi2 = NN;
        while (lo2 < hi2) { int m = (lo2 + hi2) >> 1; if (batch[m] < g + 1) lo2 = m + 1; else hi2 = m; }
        bounds[1] = lo2;
    }
    __syncthreads();
    float cnt = (float)(bounds[1] - bounds[0]); if (cnt < 1.f) cnt = 1.f;
    p[c] = pooled[g * 128 + c] / cnt;
    __syncthreads();
    float acc = bp[c];
    for (int k = 0; k < 128; ++k) acc += p[k] * Wp[k * 128 + c];
    red[c] = acc;
    __syncthreads();
    if (c < 64) {
        float s = red[c] + red[c + 64];
#pragma unroll
        for (int m = 1; m <= 32; m <<= 1) s += __shfl_xor(s, m, 64);
        if (c == 0) red[0] = s;
    }
    __syncthreads();
    float mu = red[0] * (1.f / 128.f);
    __syncthreads();
    float dv = acc - mu;
    red[c] = dv * dv;
    __syncthreads();
    if (c < 64) {
        float s = red[c] + red[c + 64];
#pragma unroll
        for (int m = 1; m <= 32; m <<= 1) s += __shfl_xor(s, m, 64);
        if (c == 0) red[0] = s;
    }
    __syncthreads();
    float var = red[0] * (1.f / 128.f);
    float rstd = rsqrtf(var + 1e-5f);
    float y = dv * rstd * gp[c] + bep[c];
    out[g * 128 + c] = silu(y);
}

extern "C" void kernel_launch(void* const* d_in, const int* in_sizes, int n_in,
                              void* d_out, int out_size, void* d_ws, size_t ws_size,
                              hipStream_t stream) {
    const float* x    = (const float*)d_in[0];
    const int*   eidx = (const int*)d_in[1];
    const int*   batch= (const int*)d_in[2];
    const float* W0   = (const float*)d_in[3];
    const float* b0   = (const float*)d_in[4];
    const float* g0   = (const float*)d_in[5];
    const float* be0  = (const float*)d_in[6];
    const float* Wg   = (const float*)d_in[7];
    const float* atts = (const float*)d_in[8];
    const float* attd = (const float*)d_in[9];
    const float* bg   = (const float*)d_in[10];
    const float* gg   = (const float*)d_in[11];
    const float* bgg  = (const float*)d_in[12];
    const float* Wp   = (const float*)d_in[13];
    const float* bp   = (const float*)d_in[14];
    const float* gp   = (const float*)d_in[15];
    const float* bep  = (const float*)d_in[16];

    char* ws = (char*)d_ws;
    size_t off = 0;
    auto alloc = [&](size_t bytes) {
        void* p = ws + off;
        off = (off + bytes + 255) & ~(size_t)255;
        return p;
    };
    unsigned short* h        = (unsigned short*)alloc((size_t)NPAD * 128 * 2);
    unsigned char*  hh8      = (unsigned char*)alloc((size_t)NN * 128);
    float*          a_s      = (float*)alloc((size_t)NN * 4 * 4);
    float*          a_d      = (float*)alloc((size_t)NN * 4 * 4);
    float*          es       = (float*)alloc((size_t)NN * 4 * 4);
    int*            offs     = (int*)alloc((size_t)(NN + 1) * 4);
    int*            csr      = (int*)alloc((size_t)EPE * 4);
    unsigned*       binned   = (unsigned*)alloc((size_t)EPE * 4);
    int*            hist_blk = (int*)alloc((size_t)NBLK * NB * 4);
    int*            blkOfs   = (int*)alloc((size_t)NBLK * NB * 4);
    int*            bktBase  = (int*)alloc((size_t)(NB + 1) * 4);
    unsigned short* WT       = (unsigned short*)alloc(4 * 16384 * 2);
    float*          pooled   = (float*)alloc((size_t)BGR * 128 * 4);

    // K1: transpose + pooled-zero + per-chunk hist (all independent)
    pre_kernel<<<4 + 32 + NBLK, 256, 0, stream>>>(W0, Wg, WT, pooled, eidx, hist_blk);
    // K2: bucket scan (1 block) hidden under encoder GEMM
    scan_encoder_kernel<<<1 + NPAD / 64, 256, 0, stream>>>(hist_blk, blkOfs, bktBase,
                                                           x, WT, b0, g0, be0, h);
    // K3: edge binning hidden under GAT GEMM layer 0
    bin_gat_kernel<<<NBLK + NPAD / 64, 256, 0, stream>>>(eidx, blkOfs, binned,
                                                         h, WT + 16384, atts, attd,
                                                         hh8, a_s, a_d, es);
    build_csr<<<NB, 256, 0, stream>>>(binned, bktBase, offs, csr);

    gat_aggregate<<<NN / 8, 256, 0, stream>>>(offs, csr, a_s, a_d, es, hh8, h,
                                              bg, gg, bgg);
    for (int l = 1; l < 3; ++l) {
        gemm_gat<<<NPAD / 64, 256, 0, stream>>>(h, WT + (l + 1) * 16384,
                                                atts + l * 128, attd + l * 128,
                                                hh8, a_s, a_d, es);
        gat_aggregate<<<NN / 8, 256, 0, stream>>>(offs, csr, a_s, a_d, es, hh8, h,
                                                  bg + l * 128, gg + l * 128,
                                                  bgg + l * 128);
    }
    pool_kernel<<<(NN + 63) / 64, 128, 0, stream>>>(h, batch, pooled);
    final_kernel<<<BGR, 128, 0, stream>>>(pooled, batch, Wp, bp, gp, bep, (float*)d_out);
}

// Round 10
// 323.429 us; speedup vs baseline: 1.6371x; 1.0524x over previous
//
#include <hip/hip_runtime.h>

#define NN    50000
#define EE    800000
#define EPE   850000     // EE + NN self loops
#define NPAD  50048      // multiple of 64
#define BGR   64
#define NB    196        // buckets of 256 nodes
#define CHUNK 4096       // edges per binning block
#define NBLK  208        // ceil(EPE / CHUNK)
#define BCAP  6144       // per-bucket LDS capacity in build_csr (mean 4337, 27 sigma)
#define AGCH  64         // edges per chunk in aggregate LDS (per node slot)

typedef __attribute__((ext_vector_type(8))) short bf16x8;
typedef __attribute__((ext_vector_type(4))) float f32x4;
typedef __attribute__((ext_vector_type(2))) float f32x2;
typedef __attribute__((ext_vector_type(4))) int   i32x4;

__device__ __forceinline__ float bf2f(unsigned short u) {
    return __uint_as_float(((unsigned)u) << 16);
}
__device__ __forceinline__ unsigned short f2bf(float f) {
    unsigned u = __float_as_uint(f);
    unsigned r = (u + 0x7FFFu + ((u >> 16) & 1u)) >> 16;
    return (unsigned short)r;
}
__device__ __forceinline__ float silu(float y) { return y / (1.f + __expf(-y)); }

// ---- K1: weight transpose (blk 0-3) + pooled zero (blk 4-35) + bucket hist (blk 36..243)
__global__ __launch_bounds__(256) void pre_kernel(const float* __restrict__ W0,
                                                  const float* __restrict__ Wg,
                                                  unsigned short* __restrict__ WT,
                                                  float* __restrict__ pooled,
                                                  const int* __restrict__ eidx,
                                                  int* __restrict__ hist_blk) {
    __shared__ unsigned short tile[128][129];
    __shared__ int lh[NB];
    int b = blockIdx.x;
    if (b < 4) {
        const float* src = (b == 0) ? W0 : (Wg + (b - 1) * 16384);
        unsigned short* dst = WT + b * 16384;
        for (int i = threadIdx.x; i < 16384; i += 256) tile[i >> 7][i & 127] = f2bf(src[i]);
        __syncthreads();
        for (int i = threadIdx.x; i < 16384; i += 256) {
            int c = i >> 7, k = i & 127;
            dst[i] = tile[k][c];
        }
    } else if (b < 36) {
        int j = (b - 4) * 256 + threadIdx.x;
        pooled[j] = 0.f;   // 32*256 == BGR*128 exactly
    } else {
        int cb = b - 36;
        for (int t = threadIdx.x; t < NB; t += 256) lh[t] = 0;
        __syncthreads();
        int base = cb * CHUNK;
#pragma unroll
        for (int j = 0; j < CHUNK / 256; ++j) {
            int i = base + j * 256 + threadIdx.x;
            if (i < EPE) {
                int d = (i < EE) ? eidx[EE + i] : (i - EE);
                atomicAdd(&lh[d >> 8], 1);
            }
        }
        __syncthreads();
        for (int t = threadIdx.x; t < NB; t += 256)
            hist_blk[cb * NB + t] = lh[t];
    }
}

// ---- K2: scan_buckets (block 0) || encoder GEMM (blocks 1..782) -------------------
__global__ __launch_bounds__(256) void scan_encoder_kernel(
    const int* __restrict__ hist_blk, int* __restrict__ blkOfs, int* __restrict__ bucketBase,
    const float* __restrict__ x, const unsigned short* __restrict__ WT,
    const float* __restrict__ b0, const float* __restrict__ g0,
    const float* __restrict__ be0, unsigned short* __restrict__ h) {
    __shared__ int tot[NB];
    __shared__ int bas[NB];
    if (blockIdx.x == 0) {
        int t = threadIdx.x;
        if (t < NB) {
            int s = 0;
            for (int k = 0; k < NBLK; ++k) s += hist_blk[k * NB + t];
            tot[t] = s;
        }
        __syncthreads();
        if (t == 0) {
            int run = 0;
            for (int b = 0; b < NB; ++b) { bas[b] = run; run += tot[b]; }
            bucketBase[NB] = EPE;
        }
        __syncthreads();
        if (t < NB) {
            int run = bas[t];
            bucketBase[t] = run;
            for (int k = 0; k < NBLK; ++k) {
                blkOfs[k * NB + t] = run;
                run += hist_blk[k * NB + t];
            }
        }
        return;
    }
    int bid = blockIdx.x - 1;
    int wave = threadIdx.x >> 6, lane = threadIdx.x & 63;
    int cl = lane & 15, q = lane >> 4;
    int row0 = bid * 64 + wave * 16;
    int rA = row0 + cl; if (rA >= NN) rA = NN - 1;
    int kq = q * 8;
    f32x4 acc[8];
#pragma unroll
    for (int t = 0; t < 8; ++t) acc[t] = (f32x4){0.f, 0.f, 0.f, 0.f};
#pragma unroll
    for (int k0 = 0; k0 < 128; k0 += 32) {
        const float* xr = x + rA * 128 + k0 + kq;
        f32x4 f0 = *(const f32x4*)(xr);
        f32x4 f1 = *(const f32x4*)(xr + 4);
        bf16x8 a;
#pragma unroll
        for (int j = 0; j < 4; ++j) {
            a[j] = (short)f2bf(f0[j]);
            a[4 + j] = (short)f2bf(f1[j]);
        }
#pragma unroll
        for (int t = 0; t < 8; ++t) {
            bf16x8 b = *(const bf16x8*)(WT + (t * 16 + cl) * 128 + k0 + kq);
            acc[t] = __builtin_amdgcn_mfma_f32_16x16x32_bf16(a, b, acc[t], 0, 0, 0);
        }
    }
    float bcol[8], gcol[8], becol[8];
#pragma unroll
    for (int t = 0; t < 8; ++t) {
        int c = t * 16 + cl;
        bcol[t] = b0[c]; gcol[t] = g0[c]; becol[t] = be0[c];
    }
#pragma unroll
    for (int r = 0; r < 4; ++r) {
        int row = row0 + q * 4 + r;
        float v[8], s = 0.f, ss = 0.f;
#pragma unroll
        for (int t = 0; t < 8; ++t) {
            v[t] = acc[t][r] + bcol[t];
            s += v[t]; ss += v[t] * v[t];
        }
#pragma unroll
        for (int m = 1; m <= 8; m <<= 1) {
            s += __shfl_xor(s, m, 64); ss += __shfl_xor(ss, m, 64);
        }
        float mu = s * (1.f / 128.f);
        float var = ss * (1.f / 128.f) - mu * mu;
        float rstd = rsqrtf(var + 1e-5f);
        if (row < NN) {
#pragma unroll
            for (int t = 0; t < 8; ++t) {
                float y = (v[t] - mu) * rstd * gcol[t] + becol[t];
                h[row * 128 + t * 16 + cl] = f2bf(silu(y));
            }
        }
    }
}

// ---- GAT GEMM body: hh8 written HEAD-INTERLEAVED: channel c -> byte (c&31)*4 + (c>>5)
__device__ __forceinline__ void gat_gemm_body(
    int bid, const unsigned short* __restrict__ h, const unsigned short* __restrict__ WT,
    const float* __restrict__ atts, const float* __restrict__ attd,
    unsigned char* __restrict__ hh8, float* __restrict__ a_s, float* __restrict__ a_d,
    float* __restrict__ es) {
    int wave = threadIdx.x >> 6, lane = threadIdx.x & 63;
    int cl = lane & 15, q = lane >> 4;
    int row0 = bid * 64 + wave * 16;
    int rA = row0 + cl; if (rA >= NN) rA = NN - 1;
    int kq = q * 8;
    f32x4 acc[8];
#pragma unroll
    for (int t = 0; t < 8; ++t) acc[t] = (f32x4){0.f, 0.f, 0.f, 0.f};
#pragma unroll
    for (int k0 = 0; k0 < 128; k0 += 32) {
        bf16x8 a = *(const bf16x8*)(h + rA * 128 + k0 + kq);
#pragma unroll
        for (int t = 0; t < 8; ++t) {
            bf16x8 b = *(const bf16x8*)(WT + (t * 16 + cl) * 128 + k0 + kq);
            acc[t] = __builtin_amdgcn_mfma_f32_16x16x32_bf16(a, b, acc[t], 0, 0, 0);
        }
    }
#pragma unroll
    for (int r = 0; r < 4; ++r) {
        int row = row0 + q * 4 + r;
        if (row < NN) {
#pragma unroll
            for (int t = 0; t < 8; ++t) {
                unsigned pk = (unsigned)__builtin_amdgcn_cvt_pk_fp8_f32(acc[t][r], acc[t][r], 0, false);
                int c = t * 16 + cl;
                hh8[row * 128 + ((c & 31) << 2) + (c >> 5)] = (unsigned char)(pk & 0xFFu);
            }
        }
    }
    float as_lo[4], as_hi[4], ad_lo[4], ad_hi[4];
#pragma unroll
    for (int hd = 0; hd < 4; ++hd) {
        as_lo[hd] = atts[hd * 32 + cl];      as_hi[hd] = atts[hd * 32 + 16 + cl];
        ad_lo[hd] = attd[hd * 32 + cl];      ad_hi[hd] = attd[hd * 32 + 16 + cl];
    }
#pragma unroll
    for (int r = 0; r < 4; ++r) {
        int row = row0 + q * 4 + r;
        float ps[4], pd[4];
#pragma unroll
        for (int hd = 0; hd < 4; ++hd) {
            float v0 = acc[2 * hd][r], v1 = acc[2 * hd + 1][r];
            ps[hd] = v0 * as_lo[hd] + v1 * as_hi[hd];
            pd[hd] = v0 * ad_lo[hd] + v1 * ad_hi[hd];
        }
#pragma unroll
        for (int m = 1; m <= 8; m <<= 1) {
#pragma unroll
            for (int hd = 0; hd < 4; ++hd) {
                ps[hd] += __shfl_xor(ps[hd], m, 64);
                pd[hd] += __shfl_xor(pd[hd], m, 64);
            }
        }
        if (row < NN && cl < 4) {
            float vs = (cl == 0) ? ps[0] : (cl == 1) ? ps[1] : (cl == 2) ? ps[2] : ps[3];
            float vd = (cl == 0) ? pd[0] : (cl == 1) ? pd[1] : (cl == 2) ? pd[2] : pd[3];
            a_s[row * 4 + cl] = vs;
            a_d[row * 4 + cl] = vd;
            float e = vs + vd;                       // self-loop logit
            es[row * 4 + cl] = (e > 0.f) ? e : 0.2f * e;
        }
    }
}

__global__ __launch_bounds__(256) void gemm_gat(
    const unsigned short* __restrict__ h, const unsigned short* __restrict__ WT,
    const float* __restrict__ atts, const float* __restrict__ attd,
    unsigned char* __restrict__ hh8, float* __restrict__ a_s, float* __restrict__ a_d,
    float* __restrict__ es) {
    gat_gemm_body(blockIdx.x, h, WT, atts, attd, hh8, a_s, a_d, es);
}

// ---- K3: bin_edges (blocks 0..207) || gemm_gat l0 (blocks 208..989) ---------------
__global__ __launch_bounds__(256) void bin_gat_kernel(
    const int* __restrict__ eidx, const int* __restrict__ blkOfs,
    unsigned* __restrict__ binned,
    const unsigned short* __restrict__ h, const unsigned short* __restrict__ WT1,
    const float* __restrict__ atts, const float* __restrict__ attd,
    unsigned char* __restrict__ hh8, float* __restrict__ a_s, float* __restrict__ a_d,
    float* __restrict__ es) {
    __shared__ unsigned staged[CHUNK];
    __shared__ int lhist[NB];
    __shared__ int lscan[NB];
    __shared__ int cnt2[NB];
    __shared__ int gofs[NB];
    if (blockIdx.x >= NBLK) {
        gat_gemm_body(blockIdx.x - NBLK, h, WT1, atts, attd, hh8, a_s, a_d, es);
        return;
    }
    int cb = blockIdx.x;
    int tid = threadIdx.x;
    for (int t = tid; t < NB; t += 256) { lhist[t] = 0; cnt2[t] = 0; }
    __syncthreads();
    int base = cb * CHUNK;
    unsigned pk[CHUNK / 256];
#pragma unroll
    for (int j = 0; j < CHUNK / 256; ++j) {
        int i = base + j * 256 + tid;
        pk[j] = 0xFFFFFFFFu;
        if (i < EPE) {
            int s, d;
            if (i < EE) { s = eidx[i]; d = eidx[EE + i]; } else { s = i - EE; d = i - EE; }
            pk[j] = ((unsigned)s << 16) | (unsigned)d;
            atomicAdd(&lhist[d >> 8], 1);
        }
    }
    __syncthreads();
    if (tid == 0) {
        int run = 0;
        for (int b = 0; b < NB; ++b) { lscan[b] = run; run += lhist[b]; }
    }
    __syncthreads();
#pragma unroll
    for (int j = 0; j < CHUNK / 256; ++j) {
        if (pk[j] != 0xFFFFFFFFu) {
            int b = (int)((pk[j] & 0xFFFFu) >> 8);
            int lp = lscan[b] + atomicAdd(&cnt2[b], 1);
            staged[lp] = pk[j];
        }
    }
    for (int t = tid; t < NB; t += 256) gofs[t] = blkOfs[cb * NB + t];
    __syncthreads();
    int nTot = lscan[NB - 1] + lhist[NB - 1];
    for (int i = tid; i < nTot; i += 256) {
        unsigned p = staged[i];
        int b = (int)((p & 0xFFFFu) >> 8);
        binned[gofs[b] + (i - lscan[b])] = p;
    }
}

// ------- per-bucket (256 nodes): counts -> offs + in-LDS sort -> contiguous csr --------
__global__ __launch_bounds__(256) void build_csr(const unsigned* __restrict__ binned,
                                                 const int* __restrict__ bucketBase,
                                                 int* __restrict__ offs,
                                                 int* __restrict__ csr) {
    __shared__ int lcsr[BCAP];
    __shared__ int lcnt[256];
    __shared__ int lcur[256];
    __shared__ int psum[256];
    int b = blockIdx.x, tid = threadIdx.x;
    int n0 = b * 256;
    int o0 = bucketBase[b];
    int nTot = bucketBase[b + 1] - o0;
    if (nTot > BCAP) nTot = BCAP;
    lcnt[tid] = 0;
    __syncthreads();
    for (int i = tid; i < nTot; i += 256)
        atomicAdd(&lcnt[binned[o0 + i] & 255u], 1);
    __syncthreads();
    int a = lcnt[tid];
    psum[tid] = a;
    __syncthreads();
    for (int d = 1; d < 256; d <<= 1) {
        int v = (tid >= d) ? psum[tid - d] : 0;
        __syncthreads(); psum[tid] += v; __syncthreads();
    }
    int excl = psum[tid] - a;
    lcur[tid] = excl;
    int node = n0 + tid;
    if (node < NN) offs[node] = o0 + excl;
    if (b == 0 && tid == 0) offs[NN] = EPE;
    __syncthreads();
    for (int i = tid; i < nTot; i += 256) {
        unsigned p = binned[o0 + i];
        int pos = atomicAdd(&lcur[p & 255u], 1);
        if (pos < BCAP) lcsr[pos] = (int)(p >> 16);
    }
    __syncthreads();
    for (int i = tid; i < nTot; i += 256)
        csr[o0 + i] = lcsr[i];
}

// ---- aggregation (round-7 proven kernel): 2 nodes/wave (8/block), 4-deep groups.
// Weight phase: 32-lane half computes (s, w4) per edge -> LDS.
// Serial phase: half walks its node's edges; per edge 1 coalesced u32 gather of
//   head-interleaved hh8: lane l32's u32 = channels {l32, 32+l32, 64+l32, 96+l32}.
// Epilogue (channels c = k*32 + l32) loads in epilogue only (round-5 spill lesson).
// Pool NOT fused (round-6 atomic-contention + round-8 occupancy lessons).
// 4-deep groups, not 8 (round-9 A/B: 8-deep = +15us).
__global__ __launch_bounds__(256) void gat_aggregate(
    const int* __restrict__ offs, const int* __restrict__ csr,
    const float* __restrict__ a_s, const float* __restrict__ a_d,
    const float* __restrict__ es, const unsigned char* __restrict__ hh8,
    unsigned short* __restrict__ h,
    const float* __restrict__ bg, const float* __restrict__ gg,
    const float* __restrict__ bgg) {
    __shared__ int   lss[8][AGCH];
    __shared__ f32x4 lww[8][AGCH];
    int wv = threadIdx.x >> 6;
    int lane = threadIdx.x & 63;
    int half = lane >> 5;
    int l32 = lane & 31;
    int ns = wv * 2 + half;
    int node = blockIdx.x * 8 + ns;     // NN % 8 == 0
    int e0 = offs[node], e1 = offs[node + 1];
    f32x4 ad4 = *(const f32x4*)(a_d + node * 4);
    f32x4 e4  = *(const f32x4*)(es  + node * 4);
    f32x4 dacc = (f32x4){0.f, 0.f, 0.f, 0.f};
    f32x4 xacc = (f32x4){0.f, 0.f, 0.f, 0.f};
    const unsigned char* hp = hh8 + l32 * 4;
    for (int base = e0; base < e1; base += AGCH) {
        int cend = min(e1, base + AGCH);
        int n = cend - base;
        // weight phase: each lane of the half computes all 4 head weights of its edges
        for (int e = base + l32; e < cend; e += 32) {
            int s = csr[e];
            f32x4 as = *(const f32x4*)(a_s + s * 4);
            f32x4 w;
#pragma unroll
            for (int k = 0; k < 4; ++k) {
                float qq = as[k] + ad4[k];
                qq = (qq > 0.f) ? qq : 0.2f * qq;
                w[k] = __expf(qq - e4[k]);
                dacc[k] += w[k];
            }
            lss[ns][e - base] = s;
            lww[ns][e - base] = w;
        }
        asm volatile("s_waitcnt lgkmcnt(0)" ::: "memory");
        // serial accumulate: all 32 lanes walk all edges; per edge one u32 gather
        int j = 0;
        for (; j + 4 <= n; j += 4) {
            int s0 = lss[ns][j],     s1 = lss[ns][j + 1];
            int s2 = lss[ns][j + 2], s3 = lss[ns][j + 3];
            f32x4 w0 = lww[ns][j],     w1 = lww[ns][j + 1];
            f32x4 w2 = lww[ns][j + 2], w3 = lww[ns][j + 3];
            unsigned v0 = *(const unsigned*)(hp + ((long)s0 << 7));
            unsigned v1 = *(const unsigned*)(hp + ((long)s1 << 7));
            unsigned v2 = *(const unsigned*)(hp + ((long)s2 << 7));
            unsigned v3 = *(const unsigned*)(hp + ((long)s3 << 7));
            f32x2 lo0 = __builtin_amdgcn_cvt_pk_f32_fp8(v0, false);
            f32x2 hi0 = __builtin_amdgcn_cvt_pk_f32_fp8(v0, true);
            f32x2 lo1 = __builtin_amdgcn_cvt_pk_f32_fp8(v1, false);
            f32x2 hi1 = __builtin_amdgcn_cvt_pk_f32_fp8(v1, true);
            f32x2 lo2 = __builtin_amdgcn_cvt_pk_f32_fp8(v2, false);
            f32x2 hi2 = __builtin_amdgcn_cvt_pk_f32_fp8(v2, true);
            f32x2 lo3 = __builtin_amdgcn_cvt_pk_f32_fp8(v3, false);
            f32x2 hi3 = __builtin_amdgcn_cvt_pk_f32_fp8(v3, true);
            xacc[0] += w0[0] * lo0[0]; xacc[1] += w0[1] * lo0[1];
            xacc[2] += w0[2] * hi0[0]; xacc[3] += w0[3] * hi0[1];
            xacc[0] += w1[0] * lo1[0]; xacc[1] += w1[1] * lo1[1];
            xacc[2] += w1[2] * hi1[0]; xacc[3] += w1[3] * hi1[1];
            xacc[0] += w2[0] * lo2[0]; xacc[1] += w2[1] * lo2[1];
            xacc[2] += w2[2] * hi2[0]; xacc[3] += w2[3] * hi2[1];
            xacc[0] += w3[0] * lo3[0]; xacc[1] += w3[1] * lo3[1];
            xacc[2] += w3[2] * hi3[0]; xacc[3] += w3[3] * hi3[1];
        }
        for (; j < n; ++j) {
            int s0 = lss[ns][j];
            f32x4 w0 = lww[ns][j];
            unsigned v0 = *(const unsigned*)(hp + ((long)s0 << 7));
            f32x2 lo0 = __builtin_amdgcn_cvt_pk_f32_fp8(v0, false);
            f32x2 hi0 = __builtin_amdgcn_cvt_pk_f32_fp8(v0, true);
            xacc[0] += w0[0] * lo0[0]; xacc[1] += w0[1] * lo0[1];
            xacc[2] += w0[2] * hi0[0]; xacc[3] += w0[3] * hi0[1];
        }
        if (cend < e1)
            asm volatile("s_waitcnt lgkmcnt(0)" ::: "memory");
    }
    // per-head denominators: reduce within the 32-lane half
#pragma unroll
    for (int m = 1; m <= 16; m <<= 1) {
#pragma unroll
        for (int k = 0; k < 4; ++k) dacc[k] += __shfl_xor(dacc[k], m, 64);
    }
    float o[4], s = 0.f, ss = 0.f;
#pragma unroll
    for (int k = 0; k < 4; ++k) {
        int c = (k << 5) + l32;
        o[k] = xacc[k] / dacc[k] + bg[c];
        s += o[k]; ss += o[k] * o[k];
    }
#pragma unroll
    for (int m = 1; m <= 16; m <<= 1) {   // reduce within the 32-lane half
        s += __shfl_xor(s, m, 64); ss += __shfl_xor(ss, m, 64);
    }
    float mu = s * (1.f / 128.f);
    float var = ss * (1.f / 128.f) - mu * mu;
    float rstd = rsqrtf(var + 1e-5f);
#pragma unroll
    for (int k = 0; k < 4; ++k) {
        int c = (k << 5) + l32;
        float y = (o[k] - mu) * rstd * gg[c] + bgg[c];
        float r = silu(y) + bf2f(h[node * 128 + c]);
        h[node * 128 + c] = f2bf(r);
    }
}

// ---- mean pool per graph (batch sorted -> run reduction, ~2 atomics per block/col) ----
__global__ void pool_kernel(const unsigned short* __restrict__ h, const int* __restrict__ batch,
                            float* __restrict__ pooled) {
    int c = threadIdx.x;
    int r0 = blockIdx.x * 64;
    int rend = r0 + 64; if (rend > NN) rend = NN;
    int cur = batch[r0];
    float acc = 0.f;
    for (int r = r0; r < rend; ++r) {
        int b = batch[r];
        float v = bf2f(h[r * 128 + c]);
        if (b != cur) {
            atomicAdd(&pooled[cur * 128 + c], acc);
            acc = 0.f; cur = b;
        }
        acc += v;
    }
    atomicAdd(&pooled[cur * 128 + c], acc);
}

// ---------------- head: silu(LN(pooled/cnt @ Wp + bp)) -> f32 out ----------------
__global__ void final_kernel(const float* __restrict__ pooled, const int* __restrict__ batch,
                             const float* __restrict__ Wp, const float* __restrict__ bp,
                             const float* __restrict__ gp, const float* __restrict__ bep,
                             float* __restrict__ out) {
    __shared__ float p[128];
    __shared__ float red[128];
    __shared__ int bounds[2];
    int g = blockIdx.x, c = threadIdx.x;
    if (c == 0) {
        int lo = 0, hi = NN;
        while (lo < hi) { int m = (lo + hi) >> 1; if (batch[m] < g) lo = m + 1; else hi = m; }
        bounds[0] = lo;
        int lo2 = lo, hi2 = NN;
        while (lo2 < hi2) { int m = (lo2 + hi2) >> 1; if (batch[m] < g + 1) lo2 = m + 1; else hi2 = m; }
        bounds[1] = lo2;
    }
    __syncthreads();
    float cnt = (float)(bounds[1] - bounds[0]); if (cnt < 1.f) cnt = 1.f;
    p[c] = pooled[g * 128 + c] / cnt;
    __syncthreads();
    float acc = bp[c];
    for (int k = 0; k < 128; ++k) acc += p[k] * Wp[k * 128 + c];
    red[c] = acc;
    __syncthreads();
    if (c < 64) {
        float s = red[c] + red[c + 64];
#pragma unroll
        for (int m = 1; m <= 32; m <<= 1) s += __shfl_xor(s, m, 64);
        if (c == 0) red[0] = s;
    }
    __syncthreads();
    float mu = red[0] * (1.f / 128.f);
    __syncthreads();
    float dv = acc - mu;
    red[c] = dv * dv;
    __syncthreads();
    if (c < 64) {
        float s = red[c] + red[c + 64];
#pragma unroll
        for (int m = 1; m <= 32; m <<= 1) s += __shfl_xor(s, m, 64);
        if (c == 0) red[0] = s;
    }
    __syncthreads();
    float var = red[0] * (1.f / 128.f);
    float rstd = rsqrtf(var + 1e-5f);
    float y = dv * rstd * gp[c] + bep[c];
    out[g * 128 + c] = silu(y);
}

extern "C" void kernel_launch(void* const* d_in, const int* in_sizes, int n_in,
                              void* d_out, int out_size, void* d_ws, size_t ws_size,
                              hipStream_t stream) {
    const float* x    = (const float*)d_in[0];
    const int*   eidx = (const int*)d_in[1];
    const int*   batch= (const int*)d_in[2];
    const float* W0   = (const float*)d_in[3];
    const float* b0   = (const float*)d_in[4];
    const float* g0   = (const float*)d_in[5];
    const float* be0  = (const float*)d_in[6];
    const float* Wg   = (const float*)d_in[7];
    const float* atts = (const float*)d_in[8];
    const float* attd = (const float*)d_in[9];
    const float* bg   = (const float*)d_in[10];
    const float* gg   = (const float*)d_in[11];
    const float* bgg  = (const float*)d_in[12];
    const float* Wp   = (const float*)d_in[13];
    const float* bp   = (const float*)d_in[14];
    const float* gp   = (const float*)d_in[15];
    const float* bep  = (const float*)d_in[16];

    char* ws = (char*)d_ws;
    size_t off = 0;
    auto alloc = [&](size_t bytes) {
        void* p = ws + off;
        off = (off + bytes + 255) & ~(size_t)255;
        return p;
    };
    unsigned short* h        = (unsigned short*)alloc((size_t)NPAD * 128 * 2);
    unsigned char*  hh8      = (unsigned char*)alloc((size_t)NN * 128);
    float*          a_s      = (float*)alloc((size_t)NN * 4 * 4);
    float*          a_d      = (float*)alloc((size_t)NN * 4 * 4);
    float*          es       = (float*)alloc((size_t)NN * 4 * 4);
    int*            offs     = (int*)alloc((size_t)(NN + 1) * 4);
    int*            csr      = (int*)alloc((size_t)EPE * 4);
    unsigned*       binned   = (unsigned*)alloc((size_t)EPE * 4);
    int*            hist_blk = (int*)alloc((size_t)NBLK * NB * 4);
    int*            blkOfs   = (int*)alloc((size_t)NBLK * NB * 4);
    int*            bktBase  = (int*)alloc((size_t)(NB + 1) * 4);
    unsigned short* WT       = (unsigned short*)alloc(4 * 16384 * 2);
    float*          pooled   = (float*)alloc((size_t)BGR * 128 * 4);

    // K1: transpose + pooled-zero + per-chunk hist (all independent)
    pre_kernel<<<4 + 32 + NBLK, 256, 0, stream>>>(W0, Wg, WT, pooled, eidx, hist_blk);
    // K2: bucket scan (1 block) hidden under encoder GEMM
    scan_encoder_kernel<<<1 + NPAD / 64, 256, 0, stream>>>(hist_blk, blkOfs, bktBase,
                                                           x, WT, b0, g0, be0, h);
    // K3: edge binning hidden under GAT GEMM layer 0
    bin_gat_kernel<<<NBLK + NPAD / 64, 256, 0, stream>>>(eidx, blkOfs, binned,
                                                         h, WT + 16384, atts, attd,
                                                         hh8, a_s, a_d, es);
    build_csr<<<NB, 256, 0, stream>>>(binned, bktBase, offs, csr);

    gat_aggregate<<<NN / 8, 256, 0, stream>>>(offs, csr, a_s, a_d, es, hh8, h,
                                              bg, gg, bgg);
    for (int l = 1; l < 3; ++l) {
        gemm_gat<<<NPAD / 64, 256, 0, stream>>>(h, WT + (l + 1) * 16384,
                                                atts + l * 128, attd + l * 128,
                                                hh8, a_s, a_d, es);
        gat_aggregate<<<NN / 8, 256, 0, stream>>>(offs, csr, a_s, a_d, es, hh8, h,
                                                  bg + l * 128, gg + l * 128,
                                                  bgg + l * 128);
    }
    pool_kernel<<<(NN + 63) / 64, 128, 0, stream>>>(h, batch, pooled);
    final_kernel<<<BGR, 128, 0, stream>>>(pooled, batch, Wp, bp, gp, bep, (float*)d_out);
}